// Round 3
// baseline (1724.189 us; speedup 1.0000x reference)
//
#include <hip/hip_runtime.h>
#include <hip/hip_fp16.h>

typedef __attribute__((ext_vector_type(4))) float floatx4;
typedef _Float16 f16x8 __attribute__((ext_vector_type(8)));

constexpr int K_TOT = 4096;
constexpr int N_TOT = 11008;
constexpr int NPACK = N_TOT / 8;     // 1376
constexpr int BM = 128, BN = 128, BK = 64;
constexpr int NKT = K_TOT / BK;      // 64
constexpr int NBN = N_TOT / BN;      // 86
constexpr int ROWB = 128;            // LDS row bytes (64 fp16) -> 8 x 16B slots

__device__ __forceinline__ int swz(int row) { return (row + (row >> 3)) & 7; }

__global__ __launch_bounds__(256, 2)
void awq_gemm(const float* __restrict__ X,
              const int* __restrict__ QW,
              const int* __restrict__ QZ,
              const float* __restrict__ SC,
              const float* __restrict__ BI,
              float* __restrict__ OUT)
{
  __shared__ __align__(16) unsigned char As[BM * ROWB];   // 16 KiB
  __shared__ __align__(16) unsigned char Bs[BN * ROWB];   // 16 KiB

  const int tid  = threadIdx.x;
  const int lane = tid & 63;
  const int wid  = tid >> 6;        // 4 waves, 2x2 grid of 64x64 outputs
  const int wm   = wid >> 1;
  const int wn   = wid & 1;

  // XCD-aware bijective swizzle (grid 5504 = 8*688)
  const int cpx = gridDim.x >> 3;
  const int lg  = (blockIdx.x & 7) * cpx + (blockIdx.x >> 3);
  const int m0  = (lg / NBN) * BM;
  const int n0  = (lg % NBN) * BN;

  // ---- A staging map: thread -> (row, k-half) ----
  const int ar = tid >> 1;          // 0..127
  const int ah = tid & 1;           // k base = 32*ah
  const float* aptr = X + (size_t)(m0 + ar) * K_TOT + ah * 32;
  const int aw_base = ar * ROWB;
  const int fa_w    = swz(ar);

  // ---- B staging map: thread -> (packed col jc, k-quad kq) ----
  const int jc = tid & 15;          // packed int32 column in tile
  const int kq = tid >> 4;          // 0..15 -> k = 4*kq .. 4*kq+3
  const int jw0 = (n0 >> 3) + jc;
  const int* qptr = QW + (size_t)(4 * kq) * NPACK + jw0;
  const int* zptr = QZ + jw0;
  const float* sptr = SC + n0 + 8 * jc;

  floatx4 acc[4][4];
  #pragma unroll
  for (int i = 0; i < 4; ++i)
    #pragma unroll
    for (int j = 0; j < 4; ++j)
      acc[i][j] = (floatx4){0.f, 0.f, 0.f, 0.f};

  // ---- prologue prefetch: tile 0 ----
  unsigned int apk[16];             // fp16-pair dwords, k-ascending
  int q[4];
  #pragma unroll
  for (int j = 0; j < 8; ++j) {
    floatx4 a = *reinterpret_cast<const floatx4*>(aptr + 4 * j);
    apk[2 * j]     = __builtin_bit_cast(unsigned int, __floats2half2_rn(a.x, a.y));
    apk[2 * j + 1] = __builtin_bit_cast(unsigned int, __floats2half2_rn(a.z, a.w));
  }
  #pragma unroll
  for (int j = 0; j < 4; ++j) q[j] = qptr[(size_t)j * NPACK];

  unsigned int zh2[4], s2[4];       // per-group: (1024+z) pairs, scale pairs

  // ---- fragment read bases ----
  const int frow = lane & 15;
  const int ksl  = lane >> 4;       // 0..3
  int aoff[4], fa[4], boff[4], fb[4];
  #pragma unroll
  for (int mf = 0; mf < 4; ++mf) {
    const int r = wm * 64 + mf * 16 + frow;
    aoff[mf] = r * ROWB; fa[mf] = swz(r);
  }
  #pragma unroll
  for (int nf = 0; nf < 4; ++nf) {
    const int r = wn * 64 + nf * 16 + frow;
    boff[nf] = r * ROWB; fb[nf] = swz(r);
  }

  for (int t = 0; t < NKT; ++t) {
    // per-group prep (group = 128 k = 2 tiles)
    if ((t & 1) == 0) {
      const int g = t >> 1;
      const unsigned int qz = (unsigned int)zptr[(size_t)g * NPACK];
      const float* sg = sptr + (size_t)g * N_TOT;
      floatx4 s0 = *reinterpret_cast<const floatx4*>(sg);
      floatx4 s1 = *reinterpret_cast<const floatx4*>(sg + 4);
      #pragma unroll
      for (int i = 0; i < 4; ++i)
        zh2[i] = ((qz >> (4 * i)) & 0x000F000Fu) | 0x64006400u;
      s2[0] = __builtin_bit_cast(unsigned int, __floats2half2_rn(s0.x, s0.y));
      s2[1] = __builtin_bit_cast(unsigned int, __floats2half2_rn(s0.z, s0.w));
      s2[2] = __builtin_bit_cast(unsigned int, __floats2half2_rn(s1.x, s1.y));
      s2[3] = __builtin_bit_cast(unsigned int, __floats2half2_rn(s1.z, s1.w));
    }

    // ---- A: regs -> LDS (4 x b128, swizzled slots) ----
    #pragma unroll
    for (int i = 0; i < 4; ++i) {
      uint4 v; v.x = apk[4*i]; v.y = apk[4*i+1]; v.z = apk[4*i+2]; v.w = apk[4*i+3];
      *reinterpret_cast<uint4*>(As + aw_base + ((((4 * ah + i) ^ fa_w)) << 4)) = v;
    }

    // ---- B: dequant + 2x2 k-transpose -> LDS (8 x b64, swizzled) ----
    #pragma unroll
    for (int i = 0; i < 4; ++i) {
      unsigned int w[4];
      #pragma unroll
      for (int j = 0; j < 4; ++j) {
        unsigned int u = (((unsigned int)q[j] >> (4 * i)) & 0x000F000Fu) | 0x64006400u;
        __half2 h = __builtin_bit_cast(__half2, u);
        __half2 d = __hmul2(__hsub2(h, __builtin_bit_cast(__half2, zh2[i])),
                            __builtin_bit_cast(__half2, s2[i]));
        w[j] = __builtin_bit_cast(unsigned int, d);
      }
      const unsigned int lo01 = (w[0] & 0xFFFFu) | (w[1] << 16);
      const unsigned int lo23 = (w[2] & 0xFFFFu) | (w[3] << 16);
      const unsigned int hi01 = (w[0] >> 16) | (w[1] & 0xFFFF0000u);
      const unsigned int hi23 = (w[2] >> 16) | (w[3] & 0xFFFF0000u);
      const int nr0 = 8 * jc + 2 * i;
      const int nr1 = nr0 + 1;
      const int hb  = (kq & 1) << 3;
      uint2 v0; v0.x = lo01; v0.y = lo23;
      uint2 v1; v1.x = hi01; v1.y = hi23;
      *reinterpret_cast<uint2*>(Bs + nr0 * ROWB + ((((kq >> 1) ^ swz(nr0)) << 4) | hb)) = v0;
      *reinterpret_cast<uint2*>(Bs + nr1 * ROWB + ((((kq >> 1) ^ swz(nr1)) << 4) | hb)) = v1;
    }

    __syncthreads();

    // ---- prefetch next tile into regs (hidden under MFMA) ----
    if (t + 1 < NKT) {
      const float* ap = aptr + (size_t)(t + 1) * BK;
      #pragma unroll
      for (int j = 0; j < 8; ++j) {
        floatx4 a = *reinterpret_cast<const floatx4*>(ap + 4 * j);
        apk[2 * j]     = __builtin_bit_cast(unsigned int, __floats2half2_rn(a.x, a.y));
        apk[2 * j + 1] = __builtin_bit_cast(unsigned int, __floats2half2_rn(a.z, a.w));
      }
      const int* qp = qptr + (size_t)(t + 1) * BK * NPACK;
      #pragma unroll
      for (int j = 0; j < 4; ++j) q[j] = qp[(size_t)j * NPACK];
    }

    // ---- fragments + 32 MFMA ----
    #pragma unroll
    for (int ks = 0; ks < 2; ++ks) {
      f16x8 af[4], bf[4];
      const int slot = ks * 4 + ksl;
      #pragma unroll
      for (int mf = 0; mf < 4; ++mf)
        af[mf] = *reinterpret_cast<const f16x8*>(As + aoff[mf] + ((slot ^ fa[mf]) << 4));
      #pragma unroll
      for (int nf = 0; nf < 4; ++nf)
        bf[nf] = *reinterpret_cast<const f16x8*>(Bs + boff[nf] + ((slot ^ fb[nf]) << 4));
      #pragma unroll
      for (int mf = 0; mf < 4; ++mf)
        #pragma unroll
        for (int nf = 0; nf < 4; ++nf)
          acc[mf][nf] = __builtin_amdgcn_mfma_f32_16x16x32_f16(
              af[mf], bf[nf], acc[mf][nf], 0, 0, 0);
    }

    __syncthreads();
  }

  // ---- epilogue: bias + fp32 store (C/D: col=lane&15, row=(lane>>4)*4+j) ----
  const int ocol = lane & 15;
  const int orow = (lane >> 4) << 2;
  #pragma unroll
  for (int nf = 0; nf < 4; ++nf) {
    const int gn = n0 + wn * 64 + nf * 16 + ocol;
    const float bv = BI[gn];
    #pragma unroll
    for (int mf = 0; mf < 4; ++mf) {
      const size_t gm = (size_t)(m0 + wm * 64 + mf * 16 + orow);
      #pragma unroll
      for (int j = 0; j < 4; ++j)
        OUT[(gm + j) * (size_t)N_TOT + gn] = acc[mf][nf][j] + bv;
    }
  }
}

extern "C" void kernel_launch(void* const* d_in, const int* in_sizes, int n_in,
                              void* d_out, int out_size, void* d_ws, size_t ws_size,
                              hipStream_t stream) {
  const float* x    = (const float*)d_in[0];
  const int*   qw   = (const int*)d_in[1];
  const int*   qz   = (const int*)d_in[2];
  const float* sc   = (const float*)d_in[3];
  const float* bias = (const float*)d_in[4];
  float* out = (float*)d_out;

  const int M = 8192;
  dim3 grid((M / BM) * NBN);          // 64 * 86 = 5504
  awq_gemm<<<grid, 256, 0, stream>>>(x, qw, qz, sc, bias, out);
}

// Round 4
// 1556.208 us; speedup vs baseline: 1.1079x; 1.1079x over previous
//
#include <hip/hip_runtime.h>
#include <hip/hip_fp16.h>

typedef __attribute__((ext_vector_type(4))) float floatx4;
typedef _Float16 f16x8 __attribute__((ext_vector_type(8)));

constexpr int K_TOT = 4096;
constexpr int N_TOT = 11008;
constexpr int NPACK = N_TOT / 8;     // 1376
constexpr int BM = 128, BN = 128, BK = 64;
constexpr int NKT = K_TOT / BK;      // 64
constexpr int NBN = N_TOT / BN;      // 86
constexpr int ROWB = 128;            // LDS row bytes (64 fp16) -> 8 x 16B slots

__device__ __forceinline__ int swz(int row) { return (row + (row >> 3)) & 7; }

__global__ __launch_bounds__(256, 2)
void awq_gemm(const float* __restrict__ X,
              const int* __restrict__ QW,
              const int* __restrict__ QZ,
              const float* __restrict__ SC,
              const float* __restrict__ BI,
              float* __restrict__ OUT)
{
  __shared__ __align__(16) unsigned char As[BM * ROWB];   // 16 KiB
  __shared__ __align__(16) unsigned char Bs[BN * ROWB];   // 16 KiB

  const int tid  = threadIdx.x;
  const int lane = tid & 63;
  const int wid  = tid >> 6;        // 4 waves, 2x2 grid of 64x64 outputs
  const int wm   = wid >> 1;
  const int wn   = wid & 1;

  // XCD-aware bijective swizzle (grid 5504 = 8*688)
  const int cpx = gridDim.x >> 3;
  const int lg  = (blockIdx.x & 7) * cpx + (blockIdx.x >> 3);
  const int m0  = (lg / NBN) * BM;
  const int n0  = (lg % NBN) * BN;

  // ---- A staging map: thread -> (row, k-half) ----
  const int ar = tid >> 1;          // 0..127
  const int ah = tid & 1;           // k base = 32*ah
  const float* aptr = X + (size_t)(m0 + ar) * K_TOT + ah * 32;
  const int aw_base = ar * ROWB;
  const int fa_w    = swz(ar);

  // ---- B staging map: thread -> (packed col jc, k-quad kq) ----
  const int jc = tid & 15;          // packed int32 column in tile
  const int kq = tid >> 4;          // 0..15 -> k = 4*kq .. 4*kq+3
  const int jw0 = (n0 >> 3) + jc;
  const int* qptr = QW + (size_t)(4 * kq) * NPACK + jw0;
  const int* zptr = QZ + jw0;
  const float* sptr = SC + n0 + 8 * jc;

  floatx4 acc[4][4];
  #pragma unroll
  for (int i = 0; i < 4; ++i)
    #pragma unroll
    for (int j = 0; j < 4; ++j)
      acc[i][j] = (floatx4){0.f, 0.f, 0.f, 0.f};

  // ---- raw prefetch registers (held across barriers; converts deferred) ----
  floatx4 araw[8];
  int q[4];
  int qz_raw;
  floatx4 sraw0, sraw1;

  // prologue: pure loads for tile 0 + group 0
  #pragma unroll
  for (int j = 0; j < 8; ++j)
    araw[j] = *reinterpret_cast<const floatx4*>(aptr + 4 * j);
  #pragma unroll
  for (int j = 0; j < 4; ++j) q[j] = qptr[(size_t)j * NPACK];
  qz_raw = zptr[0];
  sraw0 = *reinterpret_cast<const floatx4*>(sptr);
  sraw1 = *reinterpret_cast<const floatx4*>(sptr + 4);

  unsigned int zh2[4], s2[4];       // per-group: (1024+z) fp16 pairs, scale pairs

  // ---- fragment read bases ----
  const int frow = lane & 15;
  const int ksl  = lane >> 4;       // 0..3
  int aoff[4], fa[4], boff[4], fb[4];
  #pragma unroll
  for (int mf = 0; mf < 4; ++mf) {
    const int r = wm * 64 + mf * 16 + frow;
    aoff[mf] = r * ROWB; fa[mf] = swz(r);
  }
  #pragma unroll
  for (int nf = 0; nf < 4; ++nf) {
    const int r = wn * 64 + nf * 16 + frow;
    boff[nf] = r * ROWB; fb[nf] = swz(r);
  }

  for (int t = 0; t < NKT; ++t) {
    // ---- group prep from held raw regs (group = 128 k = 2 tiles) ----
    if ((t & 1) == 0) {
      #pragma unroll
      for (int i = 0; i < 4; ++i)
        zh2[i] = (((unsigned int)qz_raw >> (4 * i)) & 0x000F000Fu) | 0x64006400u;
      s2[0] = __builtin_bit_cast(unsigned int, __floats2half2_rn(sraw0.x, sraw0.y));
      s2[1] = __builtin_bit_cast(unsigned int, __floats2half2_rn(sraw0.z, sraw0.w));
      s2[2] = __builtin_bit_cast(unsigned int, __floats2half2_rn(sraw1.x, sraw1.y));
      s2[3] = __builtin_bit_cast(unsigned int, __floats2half2_rn(sraw1.z, sraw1.w));
    }

    // ---- A: convert held regs -> LDS (4 x b128, swizzled slots) ----
    #pragma unroll
    for (int i = 0; i < 4; ++i) {
      floatx4 a0 = araw[2 * i], a1 = araw[2 * i + 1];
      uint4 v;
      v.x = __builtin_bit_cast(unsigned int, __floats2half2_rn(a0.x, a0.y));
      v.y = __builtin_bit_cast(unsigned int, __floats2half2_rn(a0.z, a0.w));
      v.z = __builtin_bit_cast(unsigned int, __floats2half2_rn(a1.x, a1.y));
      v.w = __builtin_bit_cast(unsigned int, __floats2half2_rn(a1.z, a1.w));
      *reinterpret_cast<uint4*>(As + aw_base + (((4 * ah + i) ^ fa_w) << 4)) = v;
    }

    // ---- B: dequant held regs + 2x2 k-transpose -> LDS (8 x b64, swizzled) ----
    #pragma unroll
    for (int i = 0; i < 4; ++i) {
      unsigned int w[4];
      #pragma unroll
      for (int j = 0; j < 4; ++j) {
        unsigned int u = (((unsigned int)q[j] >> (4 * i)) & 0x000F000Fu) | 0x64006400u;
        __half2 h = __builtin_bit_cast(__half2, u);
        __half2 d = __hmul2(__hsub2(h, __builtin_bit_cast(__half2, zh2[i])),
                            __builtin_bit_cast(__half2, s2[i]));
        w[j] = __builtin_bit_cast(unsigned int, d);
      }
      const unsigned int lo01 = (w[0] & 0xFFFFu) | (w[1] << 16);
      const unsigned int lo23 = (w[2] & 0xFFFFu) | (w[3] << 16);
      const unsigned int hi01 = (w[0] >> 16) | (w[1] & 0xFFFF0000u);
      const unsigned int hi23 = (w[2] >> 16) | (w[3] & 0xFFFF0000u);
      const int nr0 = 8 * jc + 2 * i;
      const int nr1 = nr0 + 1;
      const int hb  = (kq & 1) << 3;
      uint2 v0; v0.x = lo01; v0.y = lo23;
      uint2 v1; v1.x = hi01; v1.y = hi23;
      *reinterpret_cast<uint2*>(Bs + nr0 * ROWB + ((((kq >> 1) ^ swz(nr0)) << 4) | hb)) = v0;
      *reinterpret_cast<uint2*>(Bs + nr1 * ROWB + ((((kq >> 1) ^ swz(nr1)) << 4) | hb)) = v1;
    }

    __syncthreads();

    // ---- prefetch next tile: PURE loads only (waitcnt lands next iteration) ----
    if (t + 1 < NKT) {
      const float* ap = aptr + (size_t)(t + 1) * BK;
      #pragma unroll
      for (int j = 0; j < 8; ++j)
        araw[j] = *reinterpret_cast<const floatx4*>(ap + 4 * j);
      const int* qp = qptr + (size_t)(t + 1) * BK * NPACK;
      #pragma unroll
      for (int j = 0; j < 4; ++j) q[j] = qp[(size_t)j * NPACK];
      if (((t + 1) & 1) == 0) {
        const int g = (t + 1) >> 1;
        qz_raw = zptr[(size_t)g * NPACK];
        const float* sg = sptr + (size_t)g * N_TOT;
        sraw0 = *reinterpret_cast<const floatx4*>(sg);
        sraw1 = *reinterpret_cast<const floatx4*>(sg + 4);
      }
    }

    // ---- fragments + 32 MFMA ----
    #pragma unroll
    for (int ks = 0; ks < 2; ++ks) {
      f16x8 af[4], bf[4];
      const int slot = ks * 4 + ksl;
      #pragma unroll
      for (int mf = 0; mf < 4; ++mf)
        af[mf] = *reinterpret_cast<const f16x8*>(As + aoff[mf] + ((slot ^ fa[mf]) << 4));
      #pragma unroll
      for (int nf = 0; nf < 4; ++nf)
        bf[nf] = *reinterpret_cast<const f16x8*>(Bs + boff[nf] + ((slot ^ fb[nf]) << 4));
      #pragma unroll
      for (int mf = 0; mf < 4; ++mf)
        #pragma unroll
        for (int nf = 0; nf < 4; ++nf)
          acc[mf][nf] = __builtin_amdgcn_mfma_f32_16x16x32_f16(
              af[mf], bf[nf], acc[mf][nf], 0, 0, 0);
    }

    __syncthreads();
  }

  // ---- epilogue: bias + fp32 store (C/D: col=lane&15, row=(lane>>4)*4+j) ----
  const int ocol = lane & 15;
  const int orow = (lane >> 4) << 2;
  #pragma unroll
  for (int nf = 0; nf < 4; ++nf) {
    const int gn = n0 + wn * 64 + nf * 16 + ocol;
    const float bv = BI[gn];
    #pragma unroll
    for (int mf = 0; mf < 4; ++mf) {
      const size_t gm = (size_t)(m0 + wm * 64 + mf * 16 + orow);
      #pragma unroll
      for (int j = 0; j < 4; ++j)
        OUT[(gm + j) * (size_t)N_TOT + gn] = acc[mf][nf][j] + bv;
    }
  }
}

extern "C" void kernel_launch(void* const* d_in, const int* in_sizes, int n_in,
                              void* d_out, int out_size, void* d_ws, size_t ws_size,
                              hipStream_t stream) {
  const float* x    = (const float*)d_in[0];
  const int*   qw   = (const int*)d_in[1];
  const int*   qz   = (const int*)d_in[2];
  const float* sc   = (const float*)d_in[3];
  const float* bias = (const float*)d_in[4];
  float* out = (float*)d_out;

  const int M = 8192;
  dim3 grid((M / BM) * NBN);          // 64 * 86 = 5504
  awq_gemm<<<grid, 256, 0, stream>>>(x, qw, qz, sc, bias, out);
}

// Round 5
// 1165.192 us; speedup vs baseline: 1.4797x; 1.3356x over previous
//
#include <hip/hip_runtime.h>
#include <hip/hip_fp16.h>
#include <hip/hip_bf16.h>

typedef __attribute__((ext_vector_type(4))) float floatx4;
typedef _Float16 f16x8 __attribute__((ext_vector_type(8)));
typedef __attribute__((ext_vector_type(8))) short short8;

constexpr int K_TOT = 4096;
constexpr int N_TOT = 11008;
constexpr int NPACK = N_TOT / 8;        // 1376
constexpr int M_TOT = 8192;

// ---------------- pass 1a: x fp32 -> fp16 ----------------
__global__ __launch_bounds__(256)
void k_cvt_x(const float* __restrict__ X, __half* __restrict__ XH, int n8) {
  int i = blockIdx.x * 256 + threadIdx.x;
  const int stride = gridDim.x * 256;
  for (; i < n8; i += stride) {
    floatx4 a = *reinterpret_cast<const floatx4*>(X + (size_t)8 * i);
    floatx4 b = *reinterpret_cast<const floatx4*>(X + (size_t)8 * i + 4);
    uint4 v;
    v.x = __builtin_bit_cast(unsigned int, __floats2half2_rn(a.x, a.y));
    v.y = __builtin_bit_cast(unsigned int, __floats2half2_rn(a.z, a.w));
    v.z = __builtin_bit_cast(unsigned int, __floats2half2_rn(b.x, b.y));
    v.w = __builtin_bit_cast(unsigned int, __floats2half2_rn(b.z, b.w));
    *reinterpret_cast<uint4*>(XH + (size_t)8 * i) = v;
  }
}

// ---------------- pass 1b: dequant + transpose -> WT[N][K] fp16 ----------------
// block tile: 128 cols x 128 k (one quant group). 86*32 = 2752 blocks.
__global__ __launch_bounds__(256)
void k_dequant(const int* __restrict__ QW, const int* __restrict__ QZ,
               const float* __restrict__ SC, __half* __restrict__ WT) {
  __shared__ __align__(16) unsigned char Ls[128 * 256];   // [col][k] fp16, 32 KiB

  const int tid  = threadIdx.x;
  const int wblk = blockIdx.x % (N_TOT / 128);            // 0..85
  const int kblk = blockIdx.x / (N_TOT / 128);            // 0..31
  const int w0 = wblk * 16;                               // packed-word col base
  const int n0 = wblk * 128;
  const int k0 = kblk * 128;
  const int g  = kblk;                                    // GROUP=128 aligns with tile

  const int jw = tid & 15;                                // word col 0..15
  const int kc = tid >> 4;                                // k-chunk 0..15 (8 k each)

  const int* qp = QW + (size_t)(k0 + 8 * kc) * NPACK + w0 + jw;
  int q[8];
  #pragma unroll
  for (int j = 0; j < 8; ++j) q[j] = qp[(size_t)j * NPACK];

  const unsigned int qz = (unsigned int)QZ[(size_t)g * NPACK + w0 + jw];
  const float* sp = SC + (size_t)g * N_TOT + (w0 + jw) * 8;
  floatx4 s0 = *reinterpret_cast<const floatx4*>(sp);
  floatx4 s1 = *reinterpret_cast<const floatx4*>(sp + 4);

  unsigned int zh[4], sh[4];
  #pragma unroll
  for (int i = 0; i < 4; ++i)
    zh[i] = ((qz >> (4 * i)) & 0x000F000Fu) | 0x64006400u;
  sh[0] = __builtin_bit_cast(unsigned int, __floats2half2_rn(s0.x, s0.y));
  sh[1] = __builtin_bit_cast(unsigned int, __floats2half2_rn(s0.z, s0.w));
  sh[2] = __builtin_bit_cast(unsigned int, __floats2half2_rn(s1.x, s1.y));
  sh[3] = __builtin_bit_cast(unsigned int, __floats2half2_rn(s1.z, s1.w));

  unsigned int d[8][4];   // [j][i] half2 = cols (2i,2i+1) at k = 8kc+j
  #pragma unroll
  for (int j = 0; j < 8; ++j)
    #pragma unroll
    for (int i = 0; i < 4; ++i) {
      unsigned int u = (((unsigned int)q[j] >> (4 * i)) & 0x000F000Fu) | 0x64006400u;
      __half2 h = __builtin_bit_cast(__half2, u);
      __half2 r = __hmul2(__hsub2(h, __builtin_bit_cast(__half2, zh[i])),
                          __builtin_bit_cast(__half2, sh[i]));
      d[j][i] = __builtin_bit_cast(unsigned int, r);
    }

  // per col c: pack 8 k's ascending -> uint4, write LDS (swizzled 16B slot)
  #pragma unroll
  for (int c = 0; c < 8; ++c) {
    uint4 v;
    unsigned int* vv = &v.x;
    #pragma unroll
    for (int p = 0; p < 4; ++p) {
      const unsigned int lo = (c & 1) ? (d[2 * p][c >> 1] >> 16)     : (d[2 * p][c >> 1] & 0xFFFFu);
      const unsigned int hi = (c & 1) ? (d[2 * p + 1][c >> 1] >> 16) : (d[2 * p + 1][c >> 1] & 0xFFFFu);
      vv[p] = lo | (hi << 16);
    }
    const int col  = 8 * jw + c;
    const int slot = kc ^ (col & 7);      // low-3-bit XOR, bijective on 0..15
    *reinterpret_cast<uint4*>(Ls + col * 256 + slot * 16) = v;
  }

  __syncthreads();

  // read back rows, store coalesced-ish (L2 merges 128B-per-thread-pair lines)
  const int r = tid >> 1;                 // col 0..127
  const int h = tid & 1;                  // k half
  __half* gout = WT + (size_t)(n0 + r) * K_TOT + k0 + h * 64;
  #pragma unroll
  for (int u = 0; u < 8; ++u) {
    const int kcr  = 8 * h + u;
    const int slot = kcr ^ (r & 7);
    uint4 v = *reinterpret_cast<const uint4*>(Ls + r * 256 + slot * 16);
    *reinterpret_cast<uint4*>(gout + u * 8) = v;
  }
}

// ---------------- pass 2: fp16 GEMM, m97-style 128x128x32, global_load_lds ----------------
constexpr int BM = 128, BN = 128, BK = 32;
constexpr int NKT = K_TOT / BK;           // 128
constexpr int NBN = N_TOT / BN;           // 86

#define GLOAD_LDS16(gp, lp)                                                      \
  __builtin_amdgcn_global_load_lds(                                              \
      (const __attribute__((address_space(1))) unsigned int*)(gp),               \
      (__attribute__((address_space(3))) unsigned int*)(lp), 16, 0, 0)

__global__ __launch_bounds__(256, 4)
void k_gemm(const __half* __restrict__ XH, const __half* __restrict__ WT,
            const float* __restrict__ BI, float* __restrict__ OUT) {
  __shared__ __align__(16) unsigned char As[BM * BK * 2];   // 8 KiB, row=64B
  __shared__ __align__(16) unsigned char Bs[BN * BK * 2];   // 8 KiB, row=64B

  const int tid  = threadIdx.x;
  const int lane = tid & 63;
  const int wid  = tid >> 6;
  const int wm   = wid >> 1;
  const int wn   = wid & 1;

  // XCD-aware bijective swizzle (grid 5504 = 8*688)
  const int cpx = gridDim.x >> 3;
  const int lg  = (blockIdx.x & 7) * cpx + (blockIdx.x >> 3);
  const int m0  = (lg / NBN) * BM;
  const int n0  = (lg % NBN) * BN;

  // staging geometry: per wave per half: 16 rows x 64B (1 KiB), lane -> (row, seg)
  const int srow = lane >> 2;       // 0..15
  const int sseg = lane & 3;        // 16B seg within 64B row
  const __half* agbase = XH + (size_t)(m0 + wid * 16 + srow) * K_TOT + sseg * 8;
  const __half* bgbase = WT + (size_t)(n0 + wid * 16 + srow) * K_TOT + sseg * 8;
  const size_t half_stride = (size_t)64 * K_TOT;   // 64 rows ahead
  unsigned char* alds = As + wid * 1024;
  unsigned char* blds = Bs + wid * 1024;

  floatx4 acc[4][4];
  #pragma unroll
  for (int i = 0; i < 4; ++i)
    #pragma unroll
    for (int j = 0; j < 4; ++j)
      acc[i][j] = (floatx4){0.f, 0.f, 0.f, 0.f};

  const int frow = lane & 15;
  const int ksl  = lane >> 4;       // 16B slot 0..3
  int aoff[4], boff[4];
  #pragma unroll
  for (int mf = 0; mf < 4; ++mf) aoff[mf] = (wm * 64 + mf * 16 + frow) * 64 + ksl * 16;
  #pragma unroll
  for (int nf = 0; nf < 4; ++nf) boff[nf] = (wn * 64 + nf * 16 + frow) * 64 + ksl * 16;

  for (int t = 0; t < NKT; ++t) {
    const size_t kadv = (size_t)t * BK;
    GLOAD_LDS16(agbase + kadv,               alds);
    GLOAD_LDS16(agbase + kadv + half_stride, alds + 4096);
    GLOAD_LDS16(bgbase + kadv,               blds);
    GLOAD_LDS16(bgbase + kadv + half_stride, blds + 4096);

    __syncthreads();

    f16x8 af[4], bf[4];
    #pragma unroll
    for (int mf = 0; mf < 4; ++mf)
      af[mf] = *reinterpret_cast<const f16x8*>(As + aoff[mf]);
    #pragma unroll
    for (int nf = 0; nf < 4; ++nf)
      bf[nf] = *reinterpret_cast<const f16x8*>(Bs + boff[nf]);
    #pragma unroll
    for (int mf = 0; mf < 4; ++mf)
      #pragma unroll
      for (int nf = 0; nf < 4; ++nf)
        acc[mf][nf] = __builtin_amdgcn_mfma_f32_16x16x32_f16(
            af[mf], bf[nf], acc[mf][nf], 0, 0, 0);

    __syncthreads();
  }

  // epilogue: bias + fp32 store (C/D: col=lane&15, row=(lane>>4)*4+j)
  const int ocol = lane & 15;
  const int orow = (lane >> 4) << 2;
  #pragma unroll
  for (int nf = 0; nf < 4; ++nf) {
    const int gn = n0 + wn * 64 + nf * 16 + ocol;
    const float bv = BI[gn];
    #pragma unroll
    for (int mf = 0; mf < 4; ++mf) {
      const size_t gm = (size_t)(m0 + wm * 64 + mf * 16 + orow);
      #pragma unroll
      for (int j = 0; j < 4; ++j)
        OUT[(gm + j) * (size_t)N_TOT + gn] = acc[mf][nf][j] + bv;
    }
  }
}

// ---------------- fallback: round-2 fused kernel (proven, 1230 us) ----------------
constexpr int FLDST = 40;
__device__ __forceinline__ unsigned short f2bf(float f) {
  __hip_bfloat16 h = __float2bfloat16(f);
  return __builtin_bit_cast(unsigned short, h);
}

__global__ __launch_bounds__(256, 2)
void awq_fallback(const float* __restrict__ X, const int* __restrict__ QW,
                  const int* __restrict__ QZ, const float* __restrict__ SC,
                  const float* __restrict__ BI, float* __restrict__ OUT) {
  __shared__ __align__(16) unsigned short As[128 * FLDST];
  __shared__ __align__(16) unsigned short Bs[128 * FLDST];
  const int tid = threadIdx.x, lane = tid & 63, wid = tid >> 6;
  const int wm = wid >> 1, wn = wid & 1;
  const int cpx = gridDim.x >> 3;
  const int lg = (blockIdx.x & 7) * cpx + (blockIdx.x >> 3);
  const int m0 = (lg / NBN) * 128, n0 = (lg % NBN) * 128;
  const int a_row = tid >> 1, a_col = (tid & 1) << 4;
  const float* aptr = X + (size_t)(m0 + a_row) * K_TOT + a_col;
  const int jc = tid & 15, kp = tid >> 4, nloc = jc << 3;
  const int* qptr = QW + (size_t)(2 * kp) * NPACK + (n0 >> 3) + jc;
  const int* zptr = QZ + (n0 >> 3) + jc;
  const float* sptr = SC + n0 + nloc;
  floatx4 acc[4][4];
  #pragma unroll
  for (int i = 0; i < 4; ++i)
    #pragma unroll
    for (int j = 0; j < 4; ++j) acc[i][j] = (floatx4){0.f, 0.f, 0.f, 0.f};
  floatx4 apre[4];
  #pragma unroll
  for (int i = 0; i < 4; ++i) apre[i] = *reinterpret_cast<const floatx4*>(aptr + 4 * i);
  int qa = qptr[0], qb = qptr[NPACK];
  float sc8[8], zs8[8];
  const int frow = lane & 15, koff = (lane >> 4) << 3;
  const int arow0 = wm * 64 + frow, brow0 = wn * 64 + frow;
  for (int t = 0; t < 128; ++t) {
    if ((t & 3) == 0) {
      const int g = t >> 2;
      const int qz = zptr[(size_t)g * NPACK];
      const floatx4* sp2 = reinterpret_cast<const floatx4*>(sptr + (size_t)g * N_TOT);
      floatx4 s0 = sp2[0], s1 = sp2[1];
      #pragma unroll
      for (int i = 0; i < 4; ++i) { sc8[i] = s0[i]; sc8[4 + i] = s1[i]; }
      constexpr int SH[8] = {0, 16, 4, 20, 8, 24, 12, 28};
      #pragma unroll
      for (int c = 0; c < 8; ++c) zs8[c] = (float)((qz >> SH[c]) & 15) * sc8[c];
    }
    {
      unsigned short tmp[16];
      #pragma unroll
      for (int i = 0; i < 4; ++i)
        #pragma unroll
        for (int j = 0; j < 4; ++j) tmp[4 * i + j] = f2bf(apre[i][j]);
      short8 lo, hi;
      #pragma unroll
      for (int j = 0; j < 8; ++j) { lo[j] = (short)tmp[j]; hi[j] = (short)tmp[8 + j]; }
      *reinterpret_cast<short8*>(&As[a_row * FLDST + a_col]) = lo;
      *reinterpret_cast<short8*>(&As[a_row * FLDST + a_col + 8]) = hi;
    }
    {
      constexpr int SH[8] = {0, 16, 4, 20, 8, 24, 12, 28};
      #pragma unroll
      for (int c = 0; c < 8; ++c) {
        float wa = (float)((qa >> SH[c]) & 15) * sc8[c] - zs8[c];
        float wb = (float)((qb >> SH[c]) & 15) * sc8[c] - zs8[c];
        unsigned int pair = (unsigned int)f2bf(wa) | ((unsigned int)f2bf(wb) << 16);
        const int n = nloc + c;
        const int kk = (2 * kp) ^ (((n >> 3) & 3) << 3);
        *reinterpret_cast<unsigned int*>(&Bs[n * FLDST + kk]) = pair;
      }
    }
    __syncthreads();
    if (t + 1 < 128) {
      const float* ap = aptr + (t + 1) * 32;
      #pragma unroll
      for (int i = 0; i < 4; ++i) apre[i] = *reinterpret_cast<const floatx4*>(ap + 4 * i);
      const int* qp = qptr + (size_t)(t + 1) * 32 * NPACK;
      qa = qp[0]; qb = qp[NPACK];
    }
    short8 af[4], bfv[4];
    #pragma unroll
    for (int mf = 0; mf < 4; ++mf)
      af[mf] = *reinterpret_cast<const short8*>(&As[(arow0 + mf * 16) * FLDST + koff]);
    #pragma unroll
    for (int nf = 0; nf < 4; ++nf) {
      const int n = brow0 + nf * 16;
      const int kk = koff ^ (((n >> 3) & 3) << 3);
      bfv[nf] = *reinterpret_cast<const short8*>(&Bs[n * FLDST + kk]);
    }
    #pragma unroll
    for (int mf = 0; mf < 4; ++mf)
      #pragma unroll
      for (int nf = 0; nf < 4; ++nf)
        acc[mf][nf] = __builtin_amdgcn_mfma_f32_16x16x32_bf16(af[mf], bfv[nf], acc[mf][nf], 0, 0, 0);
    __syncthreads();
  }
  const int ocol = lane & 15, orow = (lane >> 4) << 2;
  #pragma unroll
  for (int nf = 0; nf < 4; ++nf) {
    const int gn = n0 + wn * 64 + nf * 16 + ocol;
    const float bv = BI[gn];
    #pragma unroll
    for (int mf = 0; mf < 4; ++mf) {
      const size_t gm = (size_t)(m0 + wm * 64 + mf * 16 + orow);
      #pragma unroll
      for (int j = 0; j < 4; ++j)
        OUT[(gm + j) * (size_t)N_TOT + gn] = acc[mf][nf][j] + bv;
    }
  }
}

extern "C" void kernel_launch(void* const* d_in, const int* in_sizes, int n_in,
                              void* d_out, int out_size, void* d_ws, size_t ws_size,
                              hipStream_t stream) {
  const float* x    = (const float*)d_in[0];
  const int*   qw   = (const int*)d_in[1];
  const int*   qz   = (const int*)d_in[2];
  const float* sc   = (const float*)d_in[3];
  const float* bias = (const float*)d_in[4];
  float* out = (float*)d_out;

  const size_t XH_BYTES = (size_t)M_TOT * K_TOT * 2;       // 67,108,864
  const size_t WT_BYTES = (size_t)N_TOT * K_TOT * 2;       // 90,177,536
  const size_t NEED = XH_BYTES + WT_BYTES;                 // 150 MiB

  if (ws_size >= NEED) {
    __half* XH = (__half*)d_ws;
    __half* WT = (__half*)((char*)d_ws + XH_BYTES);
    k_cvt_x<<<2048, 256, 0, stream>>>(x, XH, M_TOT * K_TOT / 8);
    k_dequant<<<(N_TOT / 128) * (K_TOT / 128), 256, 0, stream>>>(qw, qz, sc, WT);
    k_gemm<<<(M_TOT / BM) * NBN, 256, 0, stream>>>(XH, WT, bias, out);
  } else {
    awq_fallback<<<(M_TOT / 128) * NBN, 256, 0, stream>>>(x, qw, qz, sc, bias, out);
  }
}

// Round 6
// 961.730 us; speedup vs baseline: 1.7928x; 1.2116x over previous
//
#include <hip/hip_runtime.h>
#include <hip/hip_fp16.h>
#include <hip/hip_bf16.h>

typedef __attribute__((ext_vector_type(4))) float floatx4;
typedef _Float16 f16x8 __attribute__((ext_vector_type(8)));
typedef __attribute__((ext_vector_type(8))) short short8;

constexpr int K_TOT = 4096;
constexpr int N_TOT = 11008;
constexpr int NPACK = N_TOT / 8;        // 1376
constexpr int M_TOT = 8192;

// ---------------- pass 1a: x fp32 -> fp16 ----------------
__global__ __launch_bounds__(256)
void k_cvt_x(const float* __restrict__ X, __half* __restrict__ XH, int n8) {
  int i = blockIdx.x * 256 + threadIdx.x;
  const int stride = gridDim.x * 256;
  for (; i < n8; i += stride) {
    floatx4 a = *reinterpret_cast<const floatx4*>(X + (size_t)8 * i);
    floatx4 b = *reinterpret_cast<const floatx4*>(X + (size_t)8 * i + 4);
    uint4 v;
    v.x = __builtin_bit_cast(unsigned int, __floats2half2_rn(a.x, a.y));
    v.y = __builtin_bit_cast(unsigned int, __floats2half2_rn(a.z, a.w));
    v.z = __builtin_bit_cast(unsigned int, __floats2half2_rn(b.x, b.y));
    v.w = __builtin_bit_cast(unsigned int, __floats2half2_rn(b.z, b.w));
    *reinterpret_cast<uint4*>(XH + (size_t)8 * i) = v;
  }
}

// ---------------- pass 1b: dequant + transpose -> WT[N][K] fp16 ----------------
__global__ __launch_bounds__(256)
void k_dequant(const int* __restrict__ QW, const int* __restrict__ QZ,
               const float* __restrict__ SC, __half* __restrict__ WT) {
  __shared__ __align__(16) unsigned char Ls[128 * 256];   // [col][k] fp16, 32 KiB

  const int tid  = threadIdx.x;
  const int wblk = blockIdx.x % (N_TOT / 128);
  const int kblk = blockIdx.x / (N_TOT / 128);
  const int w0 = wblk * 16;
  const int n0 = wblk * 128;
  const int k0 = kblk * 128;
  const int g  = kblk;

  const int jw = tid & 15;
  const int kc = tid >> 4;

  const int* qp = QW + (size_t)(k0 + 8 * kc) * NPACK + w0 + jw;
  int q[8];
  #pragma unroll
  for (int j = 0; j < 8; ++j) q[j] = qp[(size_t)j * NPACK];

  const unsigned int qz = (unsigned int)QZ[(size_t)g * NPACK + w0 + jw];
  const float* sp = SC + (size_t)g * N_TOT + (w0 + jw) * 8;
  floatx4 s0 = *reinterpret_cast<const floatx4*>(sp);
  floatx4 s1 = *reinterpret_cast<const floatx4*>(sp + 4);

  unsigned int zh[4], sh[4];
  #pragma unroll
  for (int i = 0; i < 4; ++i)
    zh[i] = ((qz >> (4 * i)) & 0x000F000Fu) | 0x64006400u;
  sh[0] = __builtin_bit_cast(unsigned int, __floats2half2_rn(s0.x, s0.y));
  sh[1] = __builtin_bit_cast(unsigned int, __floats2half2_rn(s0.z, s0.w));
  sh[2] = __builtin_bit_cast(unsigned int, __floats2half2_rn(s1.x, s1.y));
  sh[3] = __builtin_bit_cast(unsigned int, __floats2half2_rn(s1.z, s1.w));

  unsigned int d[8][4];
  #pragma unroll
  for (int j = 0; j < 8; ++j)
    #pragma unroll
    for (int i = 0; i < 4; ++i) {
      unsigned int u = (((unsigned int)q[j] >> (4 * i)) & 0x000F000Fu) | 0x64006400u;
      __half2 h = __builtin_bit_cast(__half2, u);
      __half2 r = __hmul2(__hsub2(h, __builtin_bit_cast(__half2, zh[i])),
                          __builtin_bit_cast(__half2, sh[i]));
      d[j][i] = __builtin_bit_cast(unsigned int, r);
    }

  #pragma unroll
  for (int c = 0; c < 8; ++c) {
    uint4 v;
    unsigned int* vv = &v.x;
    #pragma unroll
    for (int p = 0; p < 4; ++p) {
      const unsigned int lo = (c & 1) ? (d[2 * p][c >> 1] >> 16)     : (d[2 * p][c >> 1] & 0xFFFFu);
      const unsigned int hi = (c & 1) ? (d[2 * p + 1][c >> 1] >> 16) : (d[2 * p + 1][c >> 1] & 0xFFFFu);
      vv[p] = lo | (hi << 16);
    }
    const int col  = 8 * jw + c;
    const int slot = kc ^ (col & 7);
    *reinterpret_cast<uint4*>(Ls + col * 256 + slot * 16) = v;
  }

  __syncthreads();

  const int r = tid >> 1;
  const int h = tid & 1;
  __half* gout = WT + (size_t)(n0 + r) * K_TOT + k0 + h * 64;
  #pragma unroll
  for (int u = 0; u < 8; ++u) {
    const int kcr  = 8 * h + u;
    const int slot = kcr ^ (r & 7);
    uint4 v = *reinterpret_cast<const uint4*>(Ls + r * 256 + slot * 16);
    *reinterpret_cast<uint4*>(gout + u * 8) = v;
  }
}

// ---------------- pass 2: 256x256x32, 2-buffer counted-vmcnt pipeline ----------------
constexpr int NKT2 = K_TOT / 32;          // 128
constexpr int NBN2 = N_TOT / 256;         // 43

#define GLOAD_LDS16(gp, lp)                                                      \
  __builtin_amdgcn_global_load_lds(                                              \
      (const __attribute__((address_space(1))) unsigned int*)(gp),               \
      (__attribute__((address_space(3))) unsigned int*)(lp), 16, 0, 0)

template<int W> __device__ __forceinline__ void waitv() {
  if constexpr (W == 4) asm volatile("s_waitcnt vmcnt(4)" ::: "memory");
  else                  asm volatile("s_waitcnt vmcnt(0)" ::: "memory");
}

__device__ __forceinline__ int fsw(int r) { return (r + (r >> 2)) & 3; }

__global__ __launch_bounds__(512, 2)
void k_gemm(const __half* __restrict__ XH, const __half* __restrict__ WT,
            const float* __restrict__ BI, float* __restrict__ OUT) {
  __shared__ __align__(16) unsigned char Abuf[2 * 16384];   // [buf][256 rows][64 B]
  __shared__ __align__(16) unsigned char Bbuf[2 * 16384];

  const int tid  = threadIdx.x;
  const int lane = tid & 63;
  const int wid  = tid >> 6;        // 8 waves: 2(m) x 4(n)
  const int wm   = wid >> 2;
  const int wn   = wid & 3;

  // XCD-aware bijective swizzle (grid 1376 = 8*172)
  const int cpx = gridDim.x >> 3;
  const int lg  = (blockIdx.x & 7) * cpx + (blockIdx.x >> 3);
  const int m0  = (lg / NBN2) * 256;
  const int n0  = (lg % NBN2) * 256;

  // ---- staging geometry: thread -> (row r0 = tid>>2, 16B slot sp = tid&3) ----
  // LDS dest is linear (global_load_lds); source col pre-swizzled so that
  // physical slot sp holds global col 8*(sp ^ fsw(r)).
  const int r0  = tid >> 2;
  const int sp  = tid & 3;
  const int col = 8 * (sp ^ fsw(r0));     // fsw(r0+128) == fsw(r0)
  const __half* aS0 = XH + (size_t)(m0 + r0) * K_TOT + col;
  const __half* aS1 = XH + (size_t)(m0 + r0 + 128) * K_TOT + col;
  const __half* bS0 = WT + (size_t)(n0 + r0) * K_TOT + col;
  const __half* bS1 = WT + (size_t)(n0 + r0 + 128) * K_TOT + col;
  unsigned char* aldsw = Abuf + wid * 1024;
  unsigned char* bldsw = Bbuf + wid * 1024;

  auto stage = [&](int T) {
    const int cb = (T & 1) << 14;
    const size_t kb = (size_t)T * 32;
    GLOAD_LDS16(aS0 + kb, aldsw + cb);
    GLOAD_LDS16(aS1 + kb, aldsw + cb + 8192);
    GLOAD_LDS16(bS0 + kb, bldsw + cb);
    GLOAD_LDS16(bS1 + kb, bldsw + cb + 8192);
  };

  // ---- fragment read offsets (swizzled slots; 2-way bank = free) ----
  const int frow = lane & 15;
  const int ksl  = lane >> 4;       // 16B k-slot 0..3
  int aoffs[8], boffs[4];
  #pragma unroll
  for (int mf = 0; mf < 8; ++mf) {
    const int r = wm * 128 + mf * 16 + frow;
    aoffs[mf] = r * 64 + ((ksl ^ fsw(r)) << 4);
  }
  #pragma unroll
  for (int nf = 0; nf < 4; ++nf) {
    const int r = wn * 64 + nf * 16 + frow;
    boffs[nf] = r * 64 + ((ksl ^ fsw(r)) << 4);
  }

  floatx4 acc[8][4];
  #pragma unroll
  for (int i = 0; i < 8; ++i)
    #pragma unroll
    for (int j = 0; j < 4; ++j)
      acc[i][j] = (floatx4){0.f, 0.f, 0.f, 0.f};

  // prologue: stage tiles 0,1
  stage(0);
  stage(1);

  auto body = [&](int T, bool do_stage) {
    __builtin_amdgcn_s_barrier();                 // tile T visible to all waves
    __builtin_amdgcn_sched_barrier(0);
    const int cb = (T & 1) << 14;
    const unsigned char* Ab = Abuf + cb;
    const unsigned char* Bb = Bbuf + cb;
    f16x8 bfv[4], afv[8];
    #pragma unroll
    for (int nf = 0; nf < 4; ++nf)
      bfv[nf] = *reinterpret_cast<const f16x8*>(Bb + boffs[nf]);
    #pragma unroll
    for (int mf = 0; mf < 8; ++mf)
      afv[mf] = *reinterpret_cast<const f16x8*>(Ab + aoffs[mf]);
    __builtin_amdgcn_s_setprio(1);
    #pragma unroll
    for (int mf = 0; mf < 8; ++mf)
      #pragma unroll
      for (int nf = 0; nf < 4; ++nf)
        acc[mf][nf] = __builtin_amdgcn_mfma_f32_16x16x32_f16(
            afv[mf], bfv[nf], acc[mf][nf], 0, 0, 0);
    __builtin_amdgcn_s_setprio(0);
    asm volatile("" ::: "memory");                // pin ds_reads above barrier2
    __builtin_amdgcn_s_barrier();                 // all waves done reading buf
    __builtin_amdgcn_sched_barrier(0);
    if (do_stage) stage(T + 2);                   // refill just-freed buffer
  };

  for (int t = 0; t < 126; ++t) {
    waitv<4>();                                   // tile t landed; t+1 in flight
    body(t, true);
  }
  waitv<4>(); body(126, false);
  waitv<0>(); body(127, false);

  // ---- epilogue: bias + fp32 store (C/D: col=lane&15, row=(lane>>4)*4+j) ----
  const int ocol = lane & 15;
  const int orow = (lane >> 4) << 2;
  #pragma unroll
  for (int nf = 0; nf < 4; ++nf) {
    const int gn = n0 + wn * 64 + nf * 16 + ocol;
    const float bv = BI[gn];
    #pragma unroll
    for (int mf = 0; mf < 8; ++mf) {
      const size_t gm = (size_t)(m0 + wm * 128 + mf * 16 + orow);
      #pragma unroll
      for (int j = 0; j < 4; ++j)
        OUT[(gm + j) * (size_t)N_TOT + gn] = acc[mf][nf][j] + bv;
    }
  }
}

// ---------------- fallback: round-2 fused kernel (proven) ----------------
constexpr int NBN = N_TOT / 128;
constexpr int FLDST = 40;
__device__ __forceinline__ unsigned short f2bf(float f) {
  __hip_bfloat16 h = __float2bfloat16(f);
  return __builtin_bit_cast(unsigned short, h);
}

__global__ __launch_bounds__(256, 2)
void awq_fallback(const float* __restrict__ X, const int* __restrict__ QW,
                  const int* __restrict__ QZ, const float* __restrict__ SC,
                  const float* __restrict__ BI, float* __restrict__ OUT) {
  __shared__ __align__(16) unsigned short As[128 * FLDST];
  __shared__ __align__(16) unsigned short Bs[128 * FLDST];
  const int tid = threadIdx.x, lane = tid & 63, wid = tid >> 6;
  const int wm = wid >> 1, wn = wid & 1;
  const int cpx = gridDim.x >> 3;
  const int lg = (blockIdx.x & 7) * cpx + (blockIdx.x >> 3);
  const int m0 = (lg / NBN) * 128, n0 = (lg % NBN) * 128;
  const int a_row = tid >> 1, a_col = (tid & 1) << 4;
  const float* aptr = X + (size_t)(m0 + a_row) * K_TOT + a_col;
  const int jc = tid & 15, kp = tid >> 4, nloc = jc << 3;
  const int* qptr = QW + (size_t)(2 * kp) * NPACK + (n0 >> 3) + jc;
  const int* zptr = QZ + (n0 >> 3) + jc;
  const float* sptr = SC + n0 + nloc;
  floatx4 acc[4][4];
  #pragma unroll
  for (int i = 0; i < 4; ++i)
    #pragma unroll
    for (int j = 0; j < 4; ++j) acc[i][j] = (floatx4){0.f, 0.f, 0.f, 0.f};
  floatx4 apre[4];
  #pragma unroll
  for (int i = 0; i < 4; ++i) apre[i] = *reinterpret_cast<const floatx4*>(aptr + 4 * i);
  int qa = qptr[0], qb = qptr[NPACK];
  float sc8[8], zs8[8];
  const int frow = lane & 15, koff = (lane >> 4) << 3;
  const int arow0 = wm * 64 + frow, brow0 = wn * 64 + frow;
  for (int t = 0; t < 128; ++t) {
    if ((t & 3) == 0) {
      const int g = t >> 2;
      const int qz = zptr[(size_t)g * NPACK];
      const floatx4* sp2 = reinterpret_cast<const floatx4*>(sptr + (size_t)g * N_TOT);
      floatx4 s0 = sp2[0], s1 = sp2[1];
      #pragma unroll
      for (int i = 0; i < 4; ++i) { sc8[i] = s0[i]; sc8[4 + i] = s1[i]; }
      constexpr int SH[8] = {0, 16, 4, 20, 8, 24, 12, 28};
      #pragma unroll
      for (int c = 0; c < 8; ++c) zs8[c] = (float)((qz >> SH[c]) & 15) * sc8[c];
    }
    {
      unsigned short tmp[16];
      #pragma unroll
      for (int i = 0; i < 4; ++i)
        #pragma unroll
        for (int j = 0; j < 4; ++j) tmp[4 * i + j] = f2bf(apre[i][j]);
      short8 lo, hi;
      #pragma unroll
      for (int j = 0; j < 8; ++j) { lo[j] = (short)tmp[j]; hi[j] = (short)tmp[8 + j]; }
      *reinterpret_cast<short8*>(&As[a_row * FLDST + a_col]) = lo;
      *reinterpret_cast<short8*>(&As[a_row * FLDST + a_col + 8]) = hi;
    }
    {
      constexpr int SH[8] = {0, 16, 4, 20, 8, 24, 12, 28};
      #pragma unroll
      for (int c = 0; c < 8; ++c) {
        float wa = (float)((qa >> SH[c]) & 15) * sc8[c] - zs8[c];
        float wb = (float)((qb >> SH[c]) & 15) * sc8[c] - zs8[c];
        unsigned int pair = (unsigned int)f2bf(wa) | ((unsigned int)f2bf(wb) << 16);
        const int n = nloc + c;
        const int kk = koff ^ 0;
        (void)kk;
        const int kk2 = (2 * kp) ^ (((n >> 3) & 3) << 3);
        *reinterpret_cast<unsigned int*>(&Bs[n * FLDST + kk2]) = pair;
      }
    }
    __syncthreads();
    if (t + 1 < 128) {
      const float* ap = aptr + (t + 1) * 32;
      #pragma unroll
      for (int i = 0; i < 4; ++i) apre[i] = *reinterpret_cast<const floatx4*>(ap + 4 * i);
      const int* qp = qptr + (size_t)(t + 1) * 32 * NPACK;
      qa = qp[0]; qb = qp[NPACK];
    }
    short8 af[4], bfv[4];
    #pragma unroll
    for (int mf = 0; mf < 4; ++mf)
      af[mf] = *reinterpret_cast<const short8*>(&As[(arow0 + mf * 16) * FLDST + koff]);
    #pragma unroll
    for (int nf = 0; nf < 4; ++nf) {
      const int n = brow0 + nf * 16;
      const int kk = koff ^ (((n >> 3) & 3) << 3);
      bfv[nf] = *reinterpret_cast<const short8*>(&Bs[n * FLDST + kk]);
    }
    #pragma unroll
    for (int mf = 0; mf < 4; ++mf)
      #pragma unroll
      for (int nf = 0; nf < 4; ++nf)
        acc[mf][nf] = __builtin_amdgcn_mfma_f32_16x16x32_bf16(af[mf], bfv[nf], acc[mf][nf], 0, 0, 0);
    __syncthreads();
  }
  const int ocol = lane & 15, orow = (lane >> 4) << 2;
  #pragma unroll
  for (int nf = 0; nf < 4; ++nf) {
    const int gn = n0 + wn * 64 + nf * 16 + ocol;
    const float bv = BI[gn];
    #pragma unroll
    for (int mf = 0; mf < 4; ++mf) {
      const size_t gm = (size_t)(m0 + wm * 64 + mf * 16 + orow);
      #pragma unroll
      for (int j = 0; j < 4; ++j)
        OUT[(gm + j) * (size_t)N_TOT + gn] = acc[mf][nf][j] + bv;
    }
  }
}

extern "C" void kernel_launch(void* const* d_in, const int* in_sizes, int n_in,
                              void* d_out, int out_size, void* d_ws, size_t ws_size,
                              hipStream_t stream) {
  const float* x    = (const float*)d_in[0];
  const int*   qw   = (const int*)d_in[1];
  const int*   qz   = (const int*)d_in[2];
  const float* sc   = (const float*)d_in[3];
  const float* bias = (const float*)d_in[4];
  float* out = (float*)d_out;

  const size_t XH_BYTES = (size_t)M_TOT * K_TOT * 2;
  const size_t WT_BYTES = (size_t)N_TOT * K_TOT * 2;
  const size_t NEED = XH_BYTES + WT_BYTES;

  if (ws_size >= NEED) {
    __half* XH = (__half*)d_ws;
    __half* WT = (__half*)((char*)d_ws + XH_BYTES);
    k_cvt_x<<<2048, 256, 0, stream>>>(x, XH, M_TOT * K_TOT / 8);
    k_dequant<<<(N_TOT / 128) * (K_TOT / 128), 256, 0, stream>>>(qw, qz, sc, WT);
    k_gemm<<<(M_TOT / 256) * NBN2, 512, 0, stream>>>(XH, WT, bias, out);
  } else {
    awq_fallback<<<(M_TOT / 128) * NBN, 256, 0, stream>>>(x, qw, qz, sc, bias, out);
  }
}

// Round 7
// 852.619 us; speedup vs baseline: 2.0222x; 1.1280x over previous
//
#include <hip/hip_runtime.h>
#include <hip/hip_fp16.h>
#include <hip/hip_bf16.h>

typedef __attribute__((ext_vector_type(4))) float floatx4;
typedef _Float16 f16x8 __attribute__((ext_vector_type(8)));
typedef __attribute__((ext_vector_type(8))) short short8;

constexpr int K_TOT = 4096;
constexpr int N_TOT = 11008;
constexpr int NPACK = N_TOT / 8;        // 1376
constexpr int M_TOT = 8192;

// ---------------- pass 1a: x fp32 -> fp16 ----------------
__global__ __launch_bounds__(256)
void k_cvt_x(const float* __restrict__ X, __half* __restrict__ XH, int n8) {
  int i = blockIdx.x * 256 + threadIdx.x;
  const int stride = gridDim.x * 256;
  for (; i < n8; i += stride) {
    floatx4 a = *reinterpret_cast<const floatx4*>(X + (size_t)8 * i);
    floatx4 b = *reinterpret_cast<const floatx4*>(X + (size_t)8 * i + 4);
    uint4 v;
    v.x = __builtin_bit_cast(unsigned int, __floats2half2_rn(a.x, a.y));
    v.y = __builtin_bit_cast(unsigned int, __floats2half2_rn(a.z, a.w));
    v.z = __builtin_bit_cast(unsigned int, __floats2half2_rn(b.x, b.y));
    v.w = __builtin_bit_cast(unsigned int, __floats2half2_rn(b.z, b.w));
    *reinterpret_cast<uint4*>(XH + (size_t)8 * i) = v;
  }
}

// ---------------- pass 1b: dequant + transpose -> WT[N][K] fp16 ----------------
__global__ __launch_bounds__(256)
void k_dequant(const int* __restrict__ QW, const int* __restrict__ QZ,
               const float* __restrict__ SC, __half* __restrict__ WT) {
  __shared__ __align__(16) unsigned char Ls[128 * 256];   // [col][k] fp16, 32 KiB

  const int tid  = threadIdx.x;
  const int wblk = blockIdx.x % (N_TOT / 128);
  const int kblk = blockIdx.x / (N_TOT / 128);
  const int w0 = wblk * 16;
  const int n0 = wblk * 128;
  const int k0 = kblk * 128;
  const int g  = kblk;

  const int jw = tid & 15;
  const int kc = tid >> 4;

  const int* qp = QW + (size_t)(k0 + 8 * kc) * NPACK + w0 + jw;
  int q[8];
  #pragma unroll
  for (int j = 0; j < 8; ++j) q[j] = qp[(size_t)j * NPACK];

  const unsigned int qz = (unsigned int)QZ[(size_t)g * NPACK + w0 + jw];
  const float* sp = SC + (size_t)g * N_TOT + (w0 + jw) * 8;
  floatx4 s0 = *reinterpret_cast<const floatx4*>(sp);
  floatx4 s1 = *reinterpret_cast<const floatx4*>(sp + 4);

  unsigned int zh[4], sh[4];
  #pragma unroll
  for (int i = 0; i < 4; ++i)
    zh[i] = ((qz >> (4 * i)) & 0x000F000Fu) | 0x64006400u;
  sh[0] = __builtin_bit_cast(unsigned int, __floats2half2_rn(s0.x, s0.y));
  sh[1] = __builtin_bit_cast(unsigned int, __floats2half2_rn(s0.z, s0.w));
  sh[2] = __builtin_bit_cast(unsigned int, __floats2half2_rn(s1.x, s1.y));
  sh[3] = __builtin_bit_cast(unsigned int, __floats2half2_rn(s1.z, s1.w));

  unsigned int d[8][4];
  #pragma unroll
  for (int j = 0; j < 8; ++j)
    #pragma unroll
    for (int i = 0; i < 4; ++i) {
      unsigned int u = (((unsigned int)q[j] >> (4 * i)) & 0x000F000Fu) | 0x64006400u;
      __half2 h = __builtin_bit_cast(__half2, u);
      __half2 r = __hmul2(__hsub2(h, __builtin_bit_cast(__half2, zh[i])),
                          __builtin_bit_cast(__half2, sh[i]));
      d[j][i] = __builtin_bit_cast(unsigned int, r);
    }

  #pragma unroll
  for (int c = 0; c < 8; ++c) {
    uint4 v;
    unsigned int* vv = &v.x;
    #pragma unroll
    for (int p = 0; p < 4; ++p) {
      const unsigned int lo = (c & 1) ? (d[2 * p][c >> 1] >> 16)     : (d[2 * p][c >> 1] & 0xFFFFu);
      const unsigned int hi = (c & 1) ? (d[2 * p + 1][c >> 1] >> 16) : (d[2 * p + 1][c >> 1] & 0xFFFFu);
      vv[p] = lo | (hi << 16);
    }
    const int col  = 8 * jw + c;
    const int slot = kc ^ (col & 7);
    *reinterpret_cast<uint4*>(Ls + col * 256 + slot * 16) = v;
  }

  __syncthreads();

  const int r = tid >> 1;
  const int h = tid & 1;
  __half* gout = WT + (size_t)(n0 + r) * K_TOT + k0 + h * 64;
  #pragma unroll
  for (int u = 0; u < 8; ++u) {
    const int kcr  = 8 * h + u;
    const int slot = kcr ^ (r & 7);
    uint4 v = *reinterpret_cast<const uint4*>(Ls + r * 256 + slot * 16);
    *reinterpret_cast<uint4*>(gout + u * 8) = v;
  }
}

// ---------------- pass 2: 256x256x32, 4-buffer single-barrier pipeline ----------------
constexpr int NKT2 = K_TOT / 32;          // 128
constexpr int NBN2 = N_TOT / 256;         // 43

#define GLOAD_LDS16(gp, lp)                                                      \
  __builtin_amdgcn_global_load_lds(                                              \
      (const __attribute__((address_space(1))) unsigned int*)(gp),               \
      (__attribute__((address_space(3))) unsigned int*)(lp), 16, 0, 0)

template<int W> __device__ __forceinline__ void waitv() {
  if constexpr (W == 4) asm volatile("s_waitcnt vmcnt(4)" ::: "memory");
  else                  asm volatile("s_waitcnt vmcnt(0)" ::: "memory");
}

// slot swizzle: uniform over the 8 bank positions for 16-consecutive-row reads
__device__ __forceinline__ int fsw(int r) { return (r >> 1) & 3; }

__global__ __launch_bounds__(512, 2)
void k_gemm(const __half* __restrict__ XH, const __half* __restrict__ WT,
            const float* __restrict__ BI, float* __restrict__ OUT) {
  // 4 buffers x 16 KiB per operand = 128 KiB total
  __shared__ __align__(16) unsigned char Abuf[4 * 16384];
  __shared__ __align__(16) unsigned char Bbuf[4 * 16384];

  const int tid  = threadIdx.x;
  const int lane = tid & 63;
  const int wid  = tid >> 6;        // 8 waves: 2(m) x 4(n)
  const int wm   = wid >> 2;
  const int wn   = wid & 3;

  // XCD-aware bijective swizzle (grid 1376 = 8*172)
  const int cpx = gridDim.x >> 3;
  const int lg  = (blockIdx.x & 7) * cpx + (blockIdx.x >> 3);
  const int m0  = (lg / NBN2) * 256;
  const int n0  = (lg % NBN2) * 256;

  // ---- staging geometry: thread -> (row r0 = tid>>2, 16B slot sp = tid&3) ----
  // LDS dest linear (global_load_lds); source col pre-swizzled: physical slot sp
  // of row r holds global k-chunk (sp ^ fsw(r)).
  const int r0  = tid >> 2;
  const int sp  = tid & 3;
  const int col = 8 * (sp ^ fsw(r0));     // fsw(r0+128) == fsw(r0)
  const __half* aS0 = XH + (size_t)(m0 + r0) * K_TOT + col;
  const __half* aS1 = XH + (size_t)(m0 + r0 + 128) * K_TOT + col;
  const __half* bS0 = WT + (size_t)(n0 + r0) * K_TOT + col;
  const __half* bS1 = WT + (size_t)(n0 + r0 + 128) * K_TOT + col;
  unsigned char* aldsw = Abuf + wid * 1024;
  unsigned char* bldsw = Bbuf + wid * 1024;

  auto stage = [&](int T) {
    const int cb = (T & 3) << 14;
    const size_t kb = (size_t)T * 32;
    GLOAD_LDS16(aS0 + kb, aldsw + cb);
    GLOAD_LDS16(aS1 + kb, aldsw + cb + 8192);
    GLOAD_LDS16(bS0 + kb, bldsw + cb);
    GLOAD_LDS16(bS1 + kb, bldsw + cb + 8192);
  };

  // ---- fragment read offsets (conflict-free swizzled slots) ----
  const int frow = lane & 15;
  const int ksl  = lane >> 4;       // 16B k-slot 0..3
  int aoffs[8], boffs[4];
  #pragma unroll
  for (int mf = 0; mf < 8; ++mf) {
    const int r = wm * 128 + mf * 16 + frow;
    aoffs[mf] = r * 64 + ((ksl ^ fsw(r)) << 4);
  }
  #pragma unroll
  for (int nf = 0; nf < 4; ++nf) {
    const int r = wn * 64 + nf * 16 + frow;
    boffs[nf] = r * 64 + ((ksl ^ fsw(r)) << 4);
  }

  floatx4 acc[8][4];
  #pragma unroll
  for (int i = 0; i < 8; ++i)
    #pragma unroll
    for (int j = 0; j < 4; ++j)
      acc[i][j] = (floatx4){0.f, 0.f, 0.f, 0.f};

  // prologue: stage tiles 0,1 (2-deep)
  stage(0);
  stage(1);

  auto body = [&](int T, bool do_stage) {
    __builtin_amdgcn_s_barrier();                 // tile T visible to all waves
    __builtin_amdgcn_sched_barrier(0);            // pin reads below barrier
    const int cb = (T & 3) << 14;
    const unsigned char* Ab = Abuf + cb;
    const unsigned char* Bb = Bbuf + cb;
    f16x8 bfv[4], afv[8];
    #pragma unroll
    for (int nf = 0; nf < 4; ++nf)
      bfv[nf] = *reinterpret_cast<const f16x8*>(Bb + boffs[nf]);
    #pragma unroll
    for (int mf = 0; mf < 8; ++mf)
      afv[mf] = *reinterpret_cast<const f16x8*>(Ab + aoffs[mf]);
    if (do_stage) stage(T + 2);                   // issue-only; lands 2 iters out
    __builtin_amdgcn_s_setprio(1);
    #pragma unroll
    for (int mf = 0; mf < 8; ++mf)
      #pragma unroll
      for (int nf = 0; nf < 4; ++nf)
        acc[mf][nf] = __builtin_amdgcn_mfma_f32_16x16x32_f16(
            afv[mf], bfv[nf], acc[mf][nf], 0, 0, 0);
    __builtin_amdgcn_s_setprio(0);
  };

  for (int t = 0; t < NKT2 - 1; ++t) {
    waitv<4>();                 // own tile-t loads landed (t+1 may stay in flight)
    body(t, t + 2 < NKT2);
  }
  waitv<0>();
  body(NKT2 - 1, false);

  // ---- epilogue: bias + fp32 store (C/D: col=lane&15, row=(lane>>4)*4+j) ----
  const int ocol = lane & 15;
  const int orow = (lane >> 4) << 2;
  #pragma unroll
  for (int nf = 0; nf < 4; ++nf) {
    const int gn = n0 + wn * 64 + nf * 16 + ocol;
    const float bv = BI[gn];
    #pragma unroll
    for (int mf = 0; mf < 8; ++mf) {
      const size_t gm = (size_t)(m0 + wm * 128 + mf * 16 + orow);
      #pragma unroll
      for (int j = 0; j < 4; ++j)
        OUT[(gm + j) * (size_t)N_TOT + gn] = acc[mf][nf][j] + bv;
    }
  }
}

// ---------------- fallback: round-2 fused kernel (proven) ----------------
constexpr int NBN = N_TOT / 128;
constexpr int FLDST = 40;
__device__ __forceinline__ unsigned short f2bf(float f) {
  __hip_bfloat16 h = __float2bfloat16(f);
  return __builtin_bit_cast(unsigned short, h);
}

__global__ __launch_bounds__(256, 2)
void awq_fallback(const float* __restrict__ X, const int* __restrict__ QW,
                  const int* __restrict__ QZ, const float* __restrict__ SC,
                  const float* __restrict__ BI, float* __restrict__ OUT) {
  __shared__ __align__(16) unsigned short As[128 * FLDST];
  __shared__ __align__(16) unsigned short Bs[128 * FLDST];
  const int tid = threadIdx.x, lane = tid & 63, wid = tid >> 6;
  const int wm = wid >> 1, wn = wid & 1;
  const int cpx = gridDim.x >> 3;
  const int lg = (blockIdx.x & 7) * cpx + (blockIdx.x >> 3);
  const int m0 = (lg / NBN) * 128, n0 = (lg % NBN) * 128;
  const int a_row = tid >> 1, a_col = (tid & 1) << 4;
  const float* aptr = X + (size_t)(m0 + a_row) * K_TOT + a_col;
  const int jc = tid & 15, kp = tid >> 4, nloc = jc << 3;
  const int* qptr = QW + (size_t)(2 * kp) * NPACK + (n0 >> 3) + jc;
  const int* zptr = QZ + (n0 >> 3) + jc;
  const float* sptr = SC + n0 + nloc;
  floatx4 acc[4][4];
  #pragma unroll
  for (int i = 0; i < 4; ++i)
    #pragma unroll
    for (int j = 0; j < 4; ++j) acc[i][j] = (floatx4){0.f, 0.f, 0.f, 0.f};
  floatx4 apre[4];
  #pragma unroll
  for (int i = 0; i < 4; ++i) apre[i] = *reinterpret_cast<const floatx4*>(aptr + 4 * i);
  int qa = qptr[0], qb = qptr[NPACK];
  float sc8[8], zs8[8];
  const int frow = lane & 15, koff = (lane >> 4) << 3;
  const int arow0 = wm * 64 + frow, brow0 = wn * 64 + frow;
  for (int t = 0; t < 128; ++t) {
    if ((t & 3) == 0) {
      const int g = t >> 2;
      const int qz = zptr[(size_t)g * NPACK];
      const floatx4* sp2 = reinterpret_cast<const floatx4*>(sptr + (size_t)g * N_TOT);
      floatx4 s0 = sp2[0], s1 = sp2[1];
      #pragma unroll
      for (int i = 0; i < 4; ++i) { sc8[i] = s0[i]; sc8[4 + i] = s1[i]; }
      constexpr int SH[8] = {0, 16, 4, 20, 8, 24, 12, 28};
      #pragma unroll
      for (int c = 0; c < 8; ++c) zs8[c] = (float)((qz >> SH[c]) & 15) * sc8[c];
    }
    {
      unsigned short tmp[16];
      #pragma unroll
      for (int i = 0; i < 4; ++i)
        #pragma unroll
        for (int j = 0; j < 4; ++j) tmp[4 * i + j] = f2bf(apre[i][j]);
      short8 lo, hi;
      #pragma unroll
      for (int j = 0; j < 8; ++j) { lo[j] = (short)tmp[j]; hi[j] = (short)tmp[8 + j]; }
      *reinterpret_cast<short8*>(&As[a_row * FLDST + a_col]) = lo;
      *reinterpret_cast<short8*>(&As[a_row * FLDST + a_col + 8]) = hi;
    }
    {
      constexpr int SH[8] = {0, 16, 4, 20, 8, 24, 12, 28};
      #pragma unroll
      for (int c = 0; c < 8; ++c) {
        float wa = (float)((qa >> SH[c]) & 15) * sc8[c] - zs8[c];
        float wb = (float)((qb >> SH[c]) & 15) * sc8[c] - zs8[c];
        unsigned int pair = (unsigned int)f2bf(wa) | ((unsigned int)f2bf(wb) << 16);
        const int n = nloc + c;
        const int kk2 = (2 * kp) ^ (((n >> 3) & 3) << 3);
        *reinterpret_cast<unsigned int*>(&Bs[n * FLDST + kk2]) = pair;
      }
    }
    __syncthreads();
    if (t + 1 < 128) {
      const float* ap = aptr + (t + 1) * 32;
      #pragma unroll
      for (int i = 0; i < 4; ++i) apre[i] = *reinterpret_cast<const floatx4*>(ap + 4 * i);
      const int* qp = qptr + (size_t)(t + 1) * 32 * NPACK;
      qa = qp[0]; qb = qp[NPACK];
    }
    short8 af[4], bfv[4];
    #pragma unroll
    for (int mf = 0; mf < 4; ++mf)
      af[mf] = *reinterpret_cast<const short8*>(&As[(arow0 + mf * 16) * FLDST + koff]);
    #pragma unroll
    for (int nf = 0; nf < 4; ++nf) {
      const int n = brow0 + nf * 16;
      const int kk = koff ^ (((n >> 3) & 3) << 3);
      bfv[nf] = *reinterpret_cast<const short8*>(&Bs[n * FLDST + kk]);
    }
    #pragma unroll
    for (int mf = 0; mf < 4; ++mf)
      #pragma unroll
      for (int nf = 0; nf < 4; ++nf)
        acc[mf][nf] = __builtin_amdgcn_mfma_f32_16x16x32_bf16(af[mf], bfv[nf], acc[mf][nf], 0, 0, 0);
    __syncthreads();
  }
  const int ocol = lane & 15, orow = (lane >> 4) << 2;
  #pragma unroll
  for (int nf = 0; nf < 4; ++nf) {
    const int gn = n0 + wn * 64 + nf * 16 + ocol;
    const float bv = BI[gn];
    #pragma unroll
    for (int mf = 0; mf < 4; ++mf) {
      const size_t gm = (size_t)(m0 + wm * 64 + mf * 16 + orow);
      #pragma unroll
      for (int j = 0; j < 4; ++j)
        OUT[(gm + j) * (size_t)N_TOT + gn] = acc[mf][nf][j] + bv;
    }
  }
}

extern "C" void kernel_launch(void* const* d_in, const int* in_sizes, int n_in,
                              void* d_out, int out_size, void* d_ws, size_t ws_size,
                              hipStream_t stream) {
  const float* x    = (const float*)d_in[0];
  const int*   qw   = (const int*)d_in[1];
  const int*   qz   = (const int*)d_in[2];
  const float* sc   = (const float*)d_in[3];
  const float* bias = (const float*)d_in[4];
  float* out = (float*)d_out;

  const size_t XH_BYTES = (size_t)M_TOT * K_TOT * 2;
  const size_t WT_BYTES = (size_t)N_TOT * K_TOT * 2;
  const size_t NEED = XH_BYTES + WT_BYTES;

  if (ws_size >= NEED) {
    __half* XH = (__half*)d_ws;
    __half* WT = (__half*)((char*)d_ws + XH_BYTES);
    k_cvt_x<<<2048, 256, 0, stream>>>(x, XH, M_TOT * K_TOT / 8);
    k_dequant<<<(N_TOT / 128) * (K_TOT / 128), 256, 0, stream>>>(qw, qz, sc, WT);
    k_gemm<<<(M_TOT / 256) * NBN2, 512, 0, stream>>>(XH, WT, bias, out);
  } else {
    awq_fallback<<<(M_TOT / 128) * NBN, 256, 0, stream>>>(x, qw, qz, sc, bias, out);
  }
}